// Round 4
// baseline (1128.994 us; speedup 1.0000x reference)
//
#include <hip/hip_runtime.h>
#include <math.h>

// ---------------------------------------------------------------------------
// SMLadaformer block on MI355X. bf16 MFMA GEMMs (16x16x32), f32 elsewhere.
// B=8, N=1024, D=1024, H=16, DEPTH=64, MLP=4096. M = B*N = 8192.
// ---------------------------------------------------------------------------

typedef __attribute__((ext_vector_type(8))) short short8;
typedef __attribute__((ext_vector_type(4))) float f32x4;

#define DEVI __device__ __forceinline__

DEVI unsigned short f2bf(float f) {
  union { float f; unsigned int u; } c; c.f = f;
  unsigned int r = c.u + 0x7fffu + ((c.u >> 16) & 1u);
  return (unsigned short)(r >> 16);
}
DEVI float bf2f(unsigned short u) {
  union { unsigned int u; float f; } c; c.u = ((unsigned int)u) << 16;
  return c.f;
}

DEVI void async16(const void* g, void* l) {
  __builtin_amdgcn_global_load_lds((const __attribute__((address_space(1))) void*)g,
                                   (__attribute__((address_space(3))) void*)l, 16, 0, 0);
}

// ---- transpose f32 [R][C] -> bf16 [C][R] --------------------------------
__global__ void transpose_bf16_k(const float* __restrict__ in,
                                 unsigned short* __restrict__ out, int R, int C) {
  __shared__ float tile[32][33];
  const int c0 = blockIdx.x * 32, r0 = blockIdx.y * 32;
  const int tx = threadIdx.x, ty = threadIdx.y;  // 32 x 8
#pragma unroll
  for (int j = 0; j < 4; j++) {
    int r = r0 + ty + j * 8, c = c0 + tx;
    if (r < R && c < C) tile[ty + j * 8][tx] = in[(size_t)r * C + c];
  }
  __syncthreads();
#pragma unroll
  for (int j = 0; j < 4; j++) {
    int c = c0 + ty + j * 8, r = r0 + tx;  // out[c][r]
    if (c < C && r < R) out[(size_t)c * R + r] = f2bf(tile[tx][ty + j * 8]);
  }
}

// ---- pad qa_b (16) -> 128 ------------------------------------------------
__global__ void pad_bias_k(const float* __restrict__ qa_b, float* __restrict__ pad) {
  int t = threadIdx.x;
  pad[t] = (t < 16) ? qa_b[t] : 0.f;
}

// ---- conditioning: h[b][j] = relu(sum_k z[b][k]*W[k][j] + bias[j]) ------
__global__ __launch_bounds__(256) void cond_h_k(const float* __restrict__ z,
                                                const float* __restrict__ W,
                                                const float* __restrict__ bias,
                                                float* __restrict__ h) {
  __shared__ float zs[8 * 1024];
  const int tid = threadIdx.x;
  for (int i = tid; i < 8 * 1024; i += 256) zs[i] = z[i];
  __syncthreads();
  const int j = blockIdx.x * 256 + tid;
  float acc[8];
#pragma unroll
  for (int b = 0; b < 8; b++) acc[b] = 0.f;
  for (int k = 0; k < 1024; k++) {
    const float w = W[(size_t)k * 1024 + j];
#pragma unroll
    for (int b = 0; b < 8; b++) acc[b] += zs[b * 1024 + k] * w;
  }
  const float bj = bias[j];
#pragma unroll
  for (int b = 0; b < 8; b++) h[b * 1024 + j] = fmaxf(acc[b] + bj, 0.f);
}

// ---- conditioning: scale/shift = h @ {gw,bw} + {gb,bb} ------------------
__global__ __launch_bounds__(256) void cond_sb_k(const float* __restrict__ h,
                                                 const float* __restrict__ Wg,
                                                 const float* __restrict__ bg,
                                                 const float* __restrict__ Wb,
                                                 const float* __restrict__ bb,
                                                 float* __restrict__ scale,
                                                 float* __restrict__ shift) {
  __shared__ float hs[8 * 1024];
  const int tid = threadIdx.x;
  for (int i = tid; i < 8 * 1024; i += 256) hs[i] = h[i];
  __syncthreads();
  const int j = blockIdx.x * 256 + tid;
  float accs[8], acct[8];
#pragma unroll
  for (int b = 0; b < 8; b++) { accs[b] = 0.f; acct[b] = 0.f; }
  for (int k = 0; k < 1024; k++) {
    const float g = Wg[(size_t)k * 1024 + j];
    const float w = Wb[(size_t)k * 1024 + j];
#pragma unroll
    for (int b = 0; b < 8; b++) {
      accs[b] += hs[b * 1024 + k] * g;
      acct[b] += hs[b * 1024 + k] * w;
    }
  }
  const float gj = bg[j], bj = bb[j];
#pragma unroll
  for (int b = 0; b < 8; b++) {
    scale[b * 1024 + j] = accs[b] + gj;
    shift[b * 1024 + j] = acct[b] + bj;
  }
}

// ---- LayerNorm(last dim) * scale[row] + shift[row] -> bf16 --------------
__global__ __launch_bounds__(256) void ln_mod_k(const float* __restrict__ x,
                                                const float* __restrict__ scale,
                                                const float* __restrict__ shift,
                                                unsigned short* __restrict__ out) {
  const int lane = threadIdx.x & 63, wid = threadIdx.x >> 6;
  const size_t row = (size_t)blockIdx.x * 4 + wid;
  const float4* xr = (const float4*)(x + row * 1024);
  float4 v[4];
  float s = 0.f, ss = 0.f;
#pragma unroll
  for (int j = 0; j < 4; j++) {
    v[j] = xr[j * 64 + lane];
    s += v[j].x + v[j].y + v[j].z + v[j].w;
    ss += v[j].x * v[j].x + v[j].y * v[j].y + v[j].z * v[j].z + v[j].w * v[j].w;
  }
#pragma unroll
  for (int o = 32; o > 0; o >>= 1) { s += __shfl_xor(s, o); ss += __shfl_xor(ss, o); }
  const float mean = s * (1.f / 1024.f);
  const float var = ss * (1.f / 1024.f) - mean * mean;
  const float inv = rsqrtf(var + 1e-6f);
  const float sc = scale[row] * inv;
  const float sh = shift[row] - mean * sc;
#pragma unroll
  for (int j = 0; j < 4; j++) {
    ushort4 o4;
    o4.x = f2bf(v[j].x * sc + sh);
    o4.y = f2bf(v[j].y * sc + sh);
    o4.z = f2bf(v[j].z * sc + sh);
    o4.w = f2bf(v[j].w * sc + sh);
    *(ushort4*)(out + row * 1024 + (size_t)(j * 64 + lane) * 4) = o4;
  }
}

// ---- GEMM: C[M,N] = A[M,K](bf16) @ BT[N,K]^T(bf16) + bias, epilogues ----
// EPI 0: +bias -> bf16 store
// EPI 1: +bias -> gelu(exact) -> bf16 store
// EPI 2: +bias + resid[idx] -> f32 store
// EPI 3: +bias -> f32 store
template <int EPI>
__global__ __launch_bounds__(256) void gemm_bf16(const unsigned short* __restrict__ A,
                                                 const unsigned short* __restrict__ BT,
                                                 const float* __restrict__ bias,
                                                 const float* __restrict__ resid,
                                                 void* __restrict__ Cout,
                                                 int M, int N, int K) {
  __shared__ unsigned short As[128 * 64];
  __shared__ unsigned short Bs[128 * 64];
  const int tid = threadIdx.x;
  const int lane = tid & 63, wid = tid >> 6;
  const int wr = wid >> 1, wc = wid & 1;
  const size_t brow = (size_t)blockIdx.y * 128;
  const size_t bcol = (size_t)blockIdx.x * 128;
  const unsigned short* Ab = A + brow * (size_t)K;
  const unsigned short* Bb = BT + bcol * (size_t)K;

  const f32x4 zero = {0.f, 0.f, 0.f, 0.f};
  f32x4 acc[4][4];
#pragma unroll
  for (int m = 0; m < 4; m++)
#pragma unroll
    for (int n = 0; n < 4; n++) acc[m][n] = zero;

  for (int k0 = 0; k0 < K; k0 += 64) {
#pragma unroll
    for (int i = 0; i < 4; i++) {
      const int eo = (i * 256 + tid) * 8;
      const int r = eo >> 6, c = eo & 63;
      async16(Ab + (size_t)r * K + (k0 + c), &As[eo]);
      async16(Bb + (size_t)r * K + (k0 + c), &Bs[eo]);
    }
    __syncthreads();
    const int lr = lane & 15, lk = (lane >> 4) * 8;
#pragma unroll
    for (int kk = 0; kk < 64; kk += 32) {
      short8 af[4], bfv[4];
#pragma unroll
      for (int m = 0; m < 4; m++)
        af[m] = *(const short8*)&As[(wr * 64 + m * 16 + lr) * 64 + kk + lk];
#pragma unroll
      for (int n = 0; n < 4; n++)
        bfv[n] = *(const short8*)&Bs[(wc * 64 + n * 16 + lr) * 64 + kk + lk];
#pragma unroll
      for (int m = 0; m < 4; m++)
#pragma unroll
        for (int n = 0; n < 4; n++)
          acc[m][n] = __builtin_amdgcn_mfma_f32_16x16x32_bf16(af[m], bfv[n], acc[m][n], 0, 0, 0);
    }
    __syncthreads();
  }

  const int lc = lane & 15, lr4 = (lane >> 4) * 4;
#pragma unroll
  for (int n = 0; n < 4; n++) {
    const size_t col = bcol + wc * 64 + n * 16 + lc;
    const float bv = bias[col];
#pragma unroll
    for (int m = 0; m < 4; m++) {
#pragma unroll
      for (int j = 0; j < 4; j++) {
        const size_t row = brow + wr * 64 + m * 16 + lr4 + j;
        const size_t idx = row * (size_t)N + col;
        float v = acc[m][n][j] + bv;
        if (EPI == 0) {
          ((unsigned short*)Cout)[idx] = f2bf(v);
        } else if (EPI == 1) {
          v = 0.5f * v * (1.0f + erff(v * 0.70710678118654752f));
          ((unsigned short*)Cout)[idx] = f2bf(v);
        } else if (EPI == 2) {
          ((float*)Cout)[idx] = v + resid[idx];
        } else {
          ((float*)Cout)[idx] = v;
        }
      }
    }
  }
}

// ---- softmax over N for each (b,h); logits [M][128] f32, attn [B*H][N] --
__global__ __launch_bounds__(256) void softmax_k(const float* __restrict__ logits,
                                                 float* __restrict__ attn) {
  const int tid = threadIdx.x;
  const int bh = blockIdx.x;  // b*16+h
  const int b = bh >> 4, h = bh & 15;
  __shared__ float redm[4];
  __shared__ float reds[4];
  float vals[4];
#pragma unroll
  for (int j = 0; j < 4; j++) {
    const int n = j * 256 + tid;
    vals[j] = logits[((size_t)b * 1024 + n) * 128 + h] * 0.125f;
  }
  float m = fmaxf(fmaxf(vals[0], vals[1]), fmaxf(vals[2], vals[3]));
#pragma unroll
  for (int o = 32; o > 0; o >>= 1) m = fmaxf(m, __shfl_xor(m, o));
  if ((tid & 63) == 0) redm[tid >> 6] = m;
  __syncthreads();
  m = fmaxf(fmaxf(redm[0], redm[1]), fmaxf(redm[2], redm[3]));
  float e[4];
  float s = 0.f;
#pragma unroll
  for (int j = 0; j < 4; j++) { e[j] = expf(vals[j] - m); s += e[j]; }
#pragma unroll
  for (int o = 32; o > 0; o >>= 1) s += __shfl_xor(s, o);
  if ((tid & 63) == 0) reds[tid >> 6] = s;
  __syncthreads();
  s = reds[0] + reds[1] + reds[2] + reds[3];
  const float invs = 1.f / s;
#pragma unroll
  for (int j = 0; j < 4; j++)
    attn[(size_t)bh * 1024 + j * 256 + tid] = e[j] * invs;
}

// ---- global_q[b,h,d] = sum_n attn[b,h,n] * Q[b,n,h*64+d] ----------------
__global__ __launch_bounds__(256) void global_q_k(const float* __restrict__ attn,
                                                  const unsigned short* __restrict__ Q,
                                                  float* __restrict__ gq) {
  const int tid = threadIdx.x;
  const int bh = blockIdx.x;
  const int b = bh >> 4, h = bh & 15;
  const int d = tid & 63, g = tid >> 6;
  const float* arow = attn + (size_t)bh * 1024;
  const unsigned short* qcol = Q + (size_t)b * 1024 * 1024 + h * 64 + d;
  float acc = 0.f;
  for (int n = g * 256; n < g * 256 + 256; n++)
    acc += arow[n] * bf2f(qcol[(size_t)n * 1024]);
  __shared__ float red[256];
  red[tid] = acc;
  __syncthreads();
  if (g == 0) gq[(size_t)bh * 64 + d] = red[d] + red[64 + d] + red[128 + d] + red[192 + d];
}

// ---- r = gq[b,h,d] * K * V (elementwise, bf16, in-place over K) ---------
__global__ __launch_bounds__(256) void r_k(const unsigned short* __restrict__ Kb,
                                           const unsigned short* __restrict__ Vb,
                                           const float* __restrict__ gq,
                                           unsigned short* __restrict__ R) {
  const size_t i = ((size_t)blockIdx.x * 256 + threadIdx.x) * 8;
  const int col = (int)(i & 1023);
  const size_t b = i >> 20;  // / (1024*1024)
  const int h = col >> 6, dd = col & 63;
  const float* g = gq + ((b << 4) + h) * 64 + dd;
  short8 kv = *(const short8*)(Kb + i);
  short8 vv = *(const short8*)(Vb + i);
  short8 r;
#pragma unroll
  for (int j = 0; j < 8; j++) {
    float f = g[j] * bf2f((unsigned short)kv[j]) * bf2f((unsigned short)vv[j]);
    r[j] = (short)f2bf(f);
  }
  *(short8*)(R + i) = r;
}

// ---------------------------------------------------------------------------
extern "C" void kernel_launch(void* const* d_in, const int* in_sizes, int n_in,
                              void* d_out, int out_size, void* d_ws, size_t ws_size,
                              hipStream_t stream) {
  (void)in_sizes; (void)n_in; (void)out_size; (void)ws_size;
  const float* inputs = (const float*)d_in[0];
  const float* z      = (const float*)d_in[1];
  const float* n1_hw = (const float*)d_in[2];  const float* n1_hb = (const float*)d_in[3];
  const float* n1_gw = (const float*)d_in[4];  const float* n1_gb = (const float*)d_in[5];
  const float* n1_bw = (const float*)d_in[6];  const float* n1_bb = (const float*)d_in[7];
  const float* wq_w  = (const float*)d_in[8];  const float* wq_b  = (const float*)d_in[9];
  const float* wk_w  = (const float*)d_in[10]; const float* wk_b  = (const float*)d_in[11];
  const float* wv_w  = (const float*)d_in[12]; const float* wv_b  = (const float*)d_in[13];
  const float* qa_w  = (const float*)d_in[14]; const float* qa_b  = (const float*)d_in[15];
  const float* out_w = (const float*)d_in[16]; const float* out_b = (const float*)d_in[17];
  const float* n2_hw = (const float*)d_in[18]; const float* n2_hb = (const float*)d_in[19];
  const float* n2_gw = (const float*)d_in[20]; const float* n2_gb = (const float*)d_in[21];
  const float* n2_bw = (const float*)d_in[22]; const float* n2_bb = (const float*)d_in[23];
  const float* mlp_w1 = (const float*)d_in[24]; const float* mlp_b1 = (const float*)d_in[25];
  const float* mlp_w2 = (const float*)d_in[26]; const float* mlp_b2 = (const float*)d_in[27];

  const int M = 8192, D = 1024, MLPD = 4096;

  char* ws = (char*)d_ws;
  size_t o = 0;
  auto alloc = [&](size_t bytes) -> char* {
    char* p = ws + o;
    o += (bytes + 255) & ~(size_t)255;
    return p;
  };
  unsigned short* wqT = (unsigned short*)alloc((size_t)D * D * 2);
  unsigned short* wkT = (unsigned short*)alloc((size_t)D * D * 2);
  unsigned short* wvT = (unsigned short*)alloc((size_t)D * D * 2);
  unsigned short* woT = (unsigned short*)alloc((size_t)D * D * 2);
  unsigned short* w1T = (unsigned short*)alloc((size_t)MLPD * D * 2);
  unsigned short* w2T = (unsigned short*)alloc((size_t)D * MLPD * 2);
  unsigned short* qaT = (unsigned short*)alloc((size_t)128 * D * 2);
  unsigned short* xn  = (unsigned short*)alloc((size_t)M * D * 2);
  char* big = alloc((size_t)M * MLPD * 2);  // 64MB: Q/K/V/logits early, hbuf late
  unsigned short* Qb = (unsigned short*)big;
  unsigned short* Kb = (unsigned short*)(big + (size_t)M * D * 2);
  unsigned short* Vb = (unsigned short*)(big + (size_t)M * D * 4);
  float* logits      = (float*)(big + (size_t)M * D * 6);  // [M][128] f32 = 4MB
  unsigned short* hbuf = (unsigned short*)big;             // [M][4096] bf16
  float* h1     = (float*)alloc(8 * 1024 * 4);
  float* h2     = (float*)alloc(8 * 1024 * 4);
  float* scale1 = (float*)alloc(8 * 1024 * 4);
  float* shift1 = (float*)alloc(8 * 1024 * 4);
  float* scale2 = (float*)alloc(8 * 1024 * 4);
  float* shift2 = (float*)alloc(8 * 1024 * 4);
  float* gq     = (float*)alloc(8 * 16 * 64 * 4);
  float* qa_b_pad = (float*)alloc(128 * 4);

  float* out0 = (float*)d_out;                    // [M][D] final output / attn_out
  float* attn = (float*)d_out + (size_t)M * D;    // [B*H][N] attention maps

  const dim3 tb(32, 8);
  // weight transposes -> bf16 [N][K]
  hipLaunchKernelGGL(transpose_bf16_k, dim3(32, 32), tb, 0, stream, wq_w, wqT, D, D);
  hipLaunchKernelGGL(transpose_bf16_k, dim3(32, 32), tb, 0, stream, wk_w, wkT, D, D);
  hipLaunchKernelGGL(transpose_bf16_k, dim3(32, 32), tb, 0, stream, wv_w, wvT, D, D);
  hipLaunchKernelGGL(transpose_bf16_k, dim3(32, 32), tb, 0, stream, out_w, woT, D, D);
  hipLaunchKernelGGL(transpose_bf16_k, dim3(128, 32), tb, 0, stream, mlp_w1, w1T, D, MLPD);
  hipLaunchKernelGGL(transpose_bf16_k, dim3(32, 128), tb, 0, stream, mlp_w2, w2T, MLPD, D);
  hipLaunchKernelGGL(transpose_bf16_k, dim3(1, 32), tb, 0, stream, qa_w, qaT, D, 16);
  hipLaunchKernelGGL(pad_bias_k, dim3(1), dim3(128), 0, stream, qa_b, qa_b_pad);

  // conditioning
  hipLaunchKernelGGL(cond_h_k, dim3(4), dim3(256), 0, stream, z, n1_hw, n1_hb, h1);
  hipLaunchKernelGGL(cond_sb_k, dim3(4), dim3(256), 0, stream, h1, n1_gw, n1_gb, n1_bw, n1_bb, scale1, shift1);
  hipLaunchKernelGGL(cond_h_k, dim3(4), dim3(256), 0, stream, z, n2_hw, n2_hb, h2);
  hipLaunchKernelGGL(cond_sb_k, dim3(4), dim3(256), 0, stream, h2, n2_gw, n2_gb, n2_bw, n2_bb, scale2, shift2);

  // LN1 -> xn (bf16)
  hipLaunchKernelGGL(ln_mod_k, dim3(M / 4), dim3(256), 0, stream, inputs, scale1, shift1, xn);

  // Q, K, V
  hipLaunchKernelGGL(gemm_bf16<0>, dim3(8, 64), dim3(256), 0, stream, xn, wqT, wq_b, (const float*)nullptr, (void*)Qb, M, D, D);
  hipLaunchKernelGGL(gemm_bf16<0>, dim3(8, 64), dim3(256), 0, stream, xn, wkT, wk_b, (const float*)nullptr, (void*)Kb, M, D, D);
  hipLaunchKernelGGL(gemm_bf16<0>, dim3(8, 64), dim3(256), 0, stream, xn, wvT, wv_b, (const float*)nullptr, (void*)Vb, M, D, D);

  // logits = Q @ qa_w + qa_b (padded to N=128)
  hipLaunchKernelGGL(gemm_bf16<3>, dim3(1, 64), dim3(256), 0, stream, Qb, qaT, qa_b_pad, (const float*)nullptr, (void*)logits, M, 128, D);

  // softmax -> attn maps (written straight into d_out region 1)
  hipLaunchKernelGGL(softmax_k, dim3(128), dim3(256), 0, stream, logits, attn);

  // global_q
  hipLaunchKernelGGL(global_q_k, dim3(128), dim3(256), 0, stream, attn, Qb, gq);

  // r = gq * K * V (in-place over K buffer)
  hipLaunchKernelGGL(r_k, dim3(M * D / 8 / 256), dim3(256), 0, stream, Kb, Vb, gq, Kb);

  // attn_out = inputs + r @ out_w + out_b  -> d_out region 0 (f32)
  hipLaunchKernelGGL(gemm_bf16<2>, dim3(8, 64), dim3(256), 0, stream, Kb, woT, out_b, inputs, (void*)out0, M, D, D);

  // LN2 -> xn (bf16)
  hipLaunchKernelGGL(ln_mod_k, dim3(M / 4), dim3(256), 0, stream, out0, scale2, shift2, xn);

  // MLP1 + exact gelu -> hbuf (bf16)
  hipLaunchKernelGGL(gemm_bf16<1>, dim3(32, 64), dim3(256), 0, stream, xn, w1T, mlp_b1, (const float*)nullptr, (void*)hbuf, M, MLPD, D);

  // MLP2 + attn_out residual -> final output (f32, in-place RMW on d_out)
  hipLaunchKernelGGL(gemm_bf16<2>, dim3(8, 64), dim3(256), 0, stream, hbuf, w2T, mlp_b2, out0, (void*)out0, M, D, MLPD);
}

// Round 5
// 682.400 us; speedup vs baseline: 1.6544x; 1.6544x over previous
//
#include <hip/hip_runtime.h>
#include <math.h>

// ---------------------------------------------------------------------------
// SMLadaformer block on MI355X. bf16 MFMA GEMMs (16x16x32), f32 elsewhere.
// B=8, N=1024, D=1024, H=16, DEPTH=64, MLP=4096. M = B*N = 8192.
// R4: conditioning matmuls (M=8 skinny) rebuilt as K-split + atomicAdd
//     (was 4-block latency-bound loops at ~154us each, half of runtime).
// ---------------------------------------------------------------------------

typedef __attribute__((ext_vector_type(8))) short short8;
typedef __attribute__((ext_vector_type(4))) float f32x4;

#define DEVI __device__ __forceinline__

DEVI unsigned short f2bf(float f) {
  union { float f; unsigned int u; } c; c.f = f;
  unsigned int r = c.u + 0x7fffu + ((c.u >> 16) & 1u);
  return (unsigned short)(r >> 16);
}
DEVI float bf2f(unsigned short u) {
  union { unsigned int u; float f; } c; c.u = ((unsigned int)u) << 16;
  return c.f;
}

DEVI void async16(const void* g, void* l) {
  __builtin_amdgcn_global_load_lds((const __attribute__((address_space(1))) void*)g,
                                   (__attribute__((address_space(3))) void*)l, 16, 0, 0);
}

// ---- transpose f32 [R][C] -> bf16 [C][R] --------------------------------
__global__ void transpose_bf16_k(const float* __restrict__ in,
                                 unsigned short* __restrict__ out, int R, int C) {
  __shared__ float tile[32][33];
  const int c0 = blockIdx.x * 32, r0 = blockIdx.y * 32;
  const int tx = threadIdx.x, ty = threadIdx.y;  // 32 x 8
#pragma unroll
  for (int j = 0; j < 4; j++) {
    int r = r0 + ty + j * 8, c = c0 + tx;
    if (r < R && c < C) tile[ty + j * 8][tx] = in[(size_t)r * C + c];
  }
  __syncthreads();
#pragma unroll
  for (int j = 0; j < 4; j++) {
    int c = c0 + ty + j * 8, r = r0 + tx;  // out[c][r]
    if (c < C && r < R) out[(size_t)c * R + r] = f2bf(tile[tx][ty + j * 8]);
  }
}

// ---- pad qa_b (16) -> 128 ------------------------------------------------
__global__ void pad_bias_k(const float* __restrict__ qa_b, float* __restrict__ pad) {
  int t = threadIdx.x;
  pad[t] = (t < 16) ? qa_b[t] : 0.f;
}

// ---- zero the conditioning accumulators (re-poison-safe init) -----------
__global__ void zero_k(float4* __restrict__ p) {
  p[blockIdx.x * 256 + threadIdx.x] = float4{0.f, 0.f, 0.f, 0.f};
}

// ---- skinny GEMM partial: acc[8][1024] += X[8,kchunk] @ W[kchunk,jtile] --
// grid (16 j-tiles, 16 k-chunks), 256 threads. NMAT=2 shares the X staging.
template <int NMAT>
__global__ __launch_bounds__(256) void skinny_k(const float* __restrict__ X,
                                                const float* __restrict__ W0,
                                                const float* __restrict__ W1,
                                                float* __restrict__ acc0,
                                                float* __restrict__ acc1) {
  const int tid = threadIdx.x;
  const int jt = blockIdx.x, kc = blockIdx.y;
  const int jl = tid & 63, kg = tid >> 6;  // 64 j-lanes x 4 k-groups
  const int jcol = jt * 64 + jl;
  __shared__ float xs[8][64];
  for (int i = tid; i < 512; i += 256) {
    const int b = i >> 6, kk = i & 63;
    xs[b][kk] = X[b * 1024 + kc * 64 + kk];
  }
  __syncthreads();
  float a0[8], a1[8];
#pragma unroll
  for (int b = 0; b < 8; b++) { a0[b] = 0.f; a1[b] = 0.f; }
#pragma unroll
  for (int kk = 0; kk < 16; kk++) {
    const int k = kg * 16 + kk;
    const float w0 = W0[(size_t)(kc * 64 + k) * 1024 + jcol];
#pragma unroll
    for (int b = 0; b < 8; b++) a0[b] += xs[b][k] * w0;
    if (NMAT == 2) {
      const float w1 = W1[(size_t)(kc * 64 + k) * 1024 + jcol];
#pragma unroll
      for (int b = 0; b < 8; b++) a1[b] += xs[b][k] * w1;
    }
  }
  __shared__ float red[256][9];  // +1 pad: stride 9 coprime with 32 banks
#pragma unroll
  for (int b = 0; b < 8; b++) red[tid][b] = a0[b];
  __syncthreads();
  if (tid < 64) {
#pragma unroll
    for (int b = 0; b < 8; b++) {
      const float s = red[tid][b] + red[tid + 64][b] + red[tid + 128][b] + red[tid + 192][b];
      atomicAdd(&acc0[b * 1024 + jcol], s);
    }
  }
  if (NMAT == 2) {
    __syncthreads();
#pragma unroll
    for (int b = 0; b < 8; b++) red[tid][b] = a1[b];
    __syncthreads();
    if (tid < 64) {
#pragma unroll
      for (int b = 0; b < 8; b++) {
        const float s = red[tid][b] + red[tid + 64][b] + red[tid + 128][b] + red[tid + 192][b];
        atomicAdd(&acc1[b * 1024 + jcol], s);
      }
    }
  }
}

// ---- h = relu(acc + hb) --------------------------------------------------
__global__ void h_epi_k(const float* __restrict__ acc, const float* __restrict__ hb,
                        float* __restrict__ h) {
  const int i = blockIdx.x * 256 + threadIdx.x;  // 8192
  h[i] = fmaxf(acc[i] + hb[i & 1023], 0.f);
}

// ---- LayerNorm(last dim) * (s_acc+gb)[row] + (t_acc+bb)[row] -> bf16 ----
__global__ __launch_bounds__(256) void ln_mod_k(const float* __restrict__ x,
                                                const float* __restrict__ s_acc,
                                                const float* __restrict__ t_acc,
                                                const float* __restrict__ gb,
                                                const float* __restrict__ bb,
                                                unsigned short* __restrict__ out) {
  const int lane = threadIdx.x & 63, wid = threadIdx.x >> 6;
  const size_t row = (size_t)blockIdx.x * 4 + wid;
  const int n = (int)(row & 1023);
  const float4* xr = (const float4*)(x + row * 1024);
  float4 v[4];
  float s = 0.f, ss = 0.f;
#pragma unroll
  for (int j = 0; j < 4; j++) {
    v[j] = xr[j * 64 + lane];
    s += v[j].x + v[j].y + v[j].z + v[j].w;
    ss += v[j].x * v[j].x + v[j].y * v[j].y + v[j].z * v[j].z + v[j].w * v[j].w;
  }
#pragma unroll
  for (int o = 32; o > 0; o >>= 1) { s += __shfl_xor(s, o); ss += __shfl_xor(ss, o); }
  const float mean = s * (1.f / 1024.f);
  const float var = ss * (1.f / 1024.f) - mean * mean;
  const float inv = rsqrtf(var + 1e-6f);
  const float scale = s_acc[row] + gb[n];
  const float shift = t_acc[row] + bb[n];
  const float sc = scale * inv;
  const float sh = shift - mean * sc;
#pragma unroll
  for (int j = 0; j < 4; j++) {
    ushort4 o4;
    o4.x = f2bf(v[j].x * sc + sh);
    o4.y = f2bf(v[j].y * sc + sh);
    o4.z = f2bf(v[j].z * sc + sh);
    o4.w = f2bf(v[j].w * sc + sh);
    *(ushort4*)(out + row * 1024 + (size_t)(j * 64 + lane) * 4) = o4;
  }
}

// ---- GEMM: C[M,N] = A[M,K](bf16) @ BT[N,K]^T(bf16) + bias, epilogues ----
// EPI 0: +bias -> bf16 store
// EPI 1: +bias -> gelu(exact) -> bf16 store
// EPI 2: +bias + resid[idx] -> f32 store
// EPI 3: +bias -> f32 store
template <int EPI>
__global__ __launch_bounds__(256) void gemm_bf16(const unsigned short* __restrict__ A,
                                                 const unsigned short* __restrict__ BT,
                                                 const float* __restrict__ bias,
                                                 const float* __restrict__ resid,
                                                 void* __restrict__ Cout,
                                                 int M, int N, int K) {
  __shared__ unsigned short As[128 * 64];
  __shared__ unsigned short Bs[128 * 64];
  const int tid = threadIdx.x;
  const int lane = tid & 63, wid = tid >> 6;
  const int wr = wid >> 1, wc = wid & 1;
  const size_t brow = (size_t)blockIdx.y * 128;
  const size_t bcol = (size_t)blockIdx.x * 128;
  const unsigned short* Ab = A + brow * (size_t)K;
  const unsigned short* Bb = BT + bcol * (size_t)K;

  const f32x4 zero = {0.f, 0.f, 0.f, 0.f};
  f32x4 acc[4][4];
#pragma unroll
  for (int m = 0; m < 4; m++)
#pragma unroll
    for (int n = 0; n < 4; n++) acc[m][n] = zero;

  for (int k0 = 0; k0 < K; k0 += 64) {
#pragma unroll
    for (int i = 0; i < 4; i++) {
      const int eo = (i * 256 + tid) * 8;
      const int r = eo >> 6, c = eo & 63;
      async16(Ab + (size_t)r * K + (k0 + c), &As[eo]);
      async16(Bb + (size_t)r * K + (k0 + c), &Bs[eo]);
    }
    __syncthreads();
    const int lr = lane & 15, lk = (lane >> 4) * 8;
#pragma unroll
    for (int kk = 0; kk < 64; kk += 32) {
      short8 af[4], bfv[4];
#pragma unroll
      for (int m = 0; m < 4; m++)
        af[m] = *(const short8*)&As[(wr * 64 + m * 16 + lr) * 64 + kk + lk];
#pragma unroll
      for (int n = 0; n < 4; n++)
        bfv[n] = *(const short8*)&Bs[(wc * 64 + n * 16 + lr) * 64 + kk + lk];
#pragma unroll
      for (int m = 0; m < 4; m++)
#pragma unroll
        for (int n = 0; n < 4; n++)
          acc[m][n] = __builtin_amdgcn_mfma_f32_16x16x32_bf16(af[m], bfv[n], acc[m][n], 0, 0, 0);
    }
    __syncthreads();
  }

  const int lc = lane & 15, lr4 = (lane >> 4) * 4;
#pragma unroll
  for (int n = 0; n < 4; n++) {
    const size_t col = bcol + wc * 64 + n * 16 + lc;
    const float bv = bias[col];
#pragma unroll
    for (int m = 0; m < 4; m++) {
#pragma unroll
      for (int j = 0; j < 4; j++) {
        const size_t row = brow + wr * 64 + m * 16 + lr4 + j;
        const size_t idx = row * (size_t)N + col;
        float v = acc[m][n][j] + bv;
        if (EPI == 0) {
          ((unsigned short*)Cout)[idx] = f2bf(v);
        } else if (EPI == 1) {
          v = 0.5f * v * (1.0f + erff(v * 0.70710678118654752f));
          ((unsigned short*)Cout)[idx] = f2bf(v);
        } else if (EPI == 2) {
          ((float*)Cout)[idx] = v + resid[idx];
        } else {
          ((float*)Cout)[idx] = v;
        }
      }
    }
  }
}

// ---- softmax over N for each (b,h); logits [M][128] f32, attn [B*H][N] --
__global__ __launch_bounds__(256) void softmax_k(const float* __restrict__ logits,
                                                 float* __restrict__ attn) {
  const int tid = threadIdx.x;
  const int bh = blockIdx.x;  // b*16+h
  const int b = bh >> 4, h = bh & 15;
  __shared__ float redm[4];
  __shared__ float reds[4];
  float vals[4];
#pragma unroll
  for (int j = 0; j < 4; j++) {
    const int n = j * 256 + tid;
    vals[j] = logits[((size_t)b * 1024 + n) * 128 + h] * 0.125f;
  }
  float m = fmaxf(fmaxf(vals[0], vals[1]), fmaxf(vals[2], vals[3]));
#pragma unroll
  for (int o = 32; o > 0; o >>= 1) m = fmaxf(m, __shfl_xor(m, o));
  if ((tid & 63) == 0) redm[tid >> 6] = m;
  __syncthreads();
  m = fmaxf(fmaxf(redm[0], redm[1]), fmaxf(redm[2], redm[3]));
  float e[4];
  float s = 0.f;
#pragma unroll
  for (int j = 0; j < 4; j++) { e[j] = expf(vals[j] - m); s += e[j]; }
#pragma unroll
  for (int o = 32; o > 0; o >>= 1) s += __shfl_xor(s, o);
  if ((tid & 63) == 0) reds[tid >> 6] = s;
  __syncthreads();
  s = reds[0] + reds[1] + reds[2] + reds[3];
  const float invs = 1.f / s;
#pragma unroll
  for (int j = 0; j < 4; j++)
    attn[(size_t)bh * 1024 + j * 256 + tid] = e[j] * invs;
}

// ---- global_q[b,h,d] = sum_n attn[b,h,n] * Q[b,n,h*64+d] ----------------
__global__ __launch_bounds__(256) void global_q_k(const float* __restrict__ attn,
                                                  const unsigned short* __restrict__ Q,
                                                  float* __restrict__ gq) {
  const int tid = threadIdx.x;
  const int bh = blockIdx.x;
  const int b = bh >> 4, h = bh & 15;
  const int d = tid & 63, g = tid >> 6;
  const float* arow = attn + (size_t)bh * 1024;
  const unsigned short* qcol = Q + (size_t)b * 1024 * 1024 + h * 64 + d;
  float acc = 0.f;
  for (int n = g * 256; n < g * 256 + 256; n++)
    acc += arow[n] * bf2f(qcol[(size_t)n * 1024]);
  __shared__ float red[256];
  red[tid] = acc;
  __syncthreads();
  if (g == 0) gq[(size_t)bh * 64 + d] = red[d] + red[64 + d] + red[128 + d] + red[192 + d];
}

// ---- r = gq[b,h,d] * K * V (elementwise, bf16, in-place over K) ---------
__global__ __launch_bounds__(256) void r_k(const unsigned short* __restrict__ Kb,
                                           const unsigned short* __restrict__ Vb,
                                           const float* __restrict__ gq,
                                           unsigned short* __restrict__ R) {
  const size_t i = ((size_t)blockIdx.x * 256 + threadIdx.x) * 8;
  const int col = (int)(i & 1023);
  const size_t b = i >> 20;  // / (1024*1024)
  const int h = col >> 6, dd = col & 63;
  const float* g = gq + ((b << 4) + h) * 64 + dd;
  short8 kv = *(const short8*)(Kb + i);
  short8 vv = *(const short8*)(Vb + i);
  short8 r;
#pragma unroll
  for (int j = 0; j < 8; j++) {
    float f = g[j] * bf2f((unsigned short)kv[j]) * bf2f((unsigned short)vv[j]);
    r[j] = (short)f2bf(f);
  }
  *(short8*)(R + i) = r;
}

// ---------------------------------------------------------------------------
extern "C" void kernel_launch(void* const* d_in, const int* in_sizes, int n_in,
                              void* d_out, int out_size, void* d_ws, size_t ws_size,
                              hipStream_t stream) {
  (void)in_sizes; (void)n_in; (void)out_size; (void)ws_size;
  const float* inputs = (const float*)d_in[0];
  const float* z      = (const float*)d_in[1];
  const float* n1_hw = (const float*)d_in[2];  const float* n1_hb = (const float*)d_in[3];
  const float* n1_gw = (const float*)d_in[4];  const float* n1_gb = (const float*)d_in[5];
  const float* n1_bw = (const float*)d_in[6];  const float* n1_bb = (const float*)d_in[7];
  const float* wq_w  = (const float*)d_in[8];  const float* wq_b  = (const float*)d_in[9];
  const float* wk_w  = (const float*)d_in[10]; const float* wk_b  = (const float*)d_in[11];
  const float* wv_w  = (const float*)d_in[12]; const float* wv_b  = (const float*)d_in[13];
  const float* qa_w  = (const float*)d_in[14]; const float* qa_b  = (const float*)d_in[15];
  const float* out_w = (const float*)d_in[16]; const float* out_b = (const float*)d_in[17];
  const float* n2_hw = (const float*)d_in[18]; const float* n2_hb = (const float*)d_in[19];
  const float* n2_gw = (const float*)d_in[20]; const float* n2_gb = (const float*)d_in[21];
  const float* n2_bw = (const float*)d_in[22]; const float* n2_bb = (const float*)d_in[23];
  const float* mlp_w1 = (const float*)d_in[24]; const float* mlp_b1 = (const float*)d_in[25];
  const float* mlp_w2 = (const float*)d_in[26]; const float* mlp_b2 = (const float*)d_in[27];

  const int M = 8192, D = 1024, MLPD = 4096;

  char* ws = (char*)d_ws;
  size_t o = 0;
  auto alloc = [&](size_t bytes) -> char* {
    char* p = ws + o;
    o += (bytes + 255) & ~(size_t)255;
    return p;
  };
  unsigned short* wqT = (unsigned short*)alloc((size_t)D * D * 2);
  unsigned short* wkT = (unsigned short*)alloc((size_t)D * D * 2);
  unsigned short* wvT = (unsigned short*)alloc((size_t)D * D * 2);
  unsigned short* woT = (unsigned short*)alloc((size_t)D * D * 2);
  unsigned short* w1T = (unsigned short*)alloc((size_t)MLPD * D * 2);
  unsigned short* w2T = (unsigned short*)alloc((size_t)D * MLPD * 2);
  unsigned short* qaT = (unsigned short*)alloc((size_t)128 * D * 2);
  unsigned short* xn  = (unsigned short*)alloc((size_t)M * D * 2);
  char* big = alloc((size_t)M * MLPD * 2);  // 64MB: Q/K/V/logits early, hbuf late
  unsigned short* Qb = (unsigned short*)big;
  unsigned short* Kb = (unsigned short*)(big + (size_t)M * D * 2);
  unsigned short* Vb = (unsigned short*)(big + (size_t)M * D * 4);
  float* logits      = (float*)(big + (size_t)M * D * 6);  // [M][128] f32 = 4MB
  unsigned short* hbuf = (unsigned short*)big;             // [M][4096] bf16
  // conditioning accumulators: [h1|s1|t1|h2|s2|t2] x [8][1024] f32 (zeroed)
  float* cacc  = (float*)alloc(6 * 8192 * 4);
  float* accH1 = cacc;
  float* accS1 = cacc + 1 * 8192;
  float* accT1 = cacc + 2 * 8192;
  float* accH2 = cacc + 3 * 8192;
  float* accS2 = cacc + 4 * 8192;
  float* accT2 = cacc + 5 * 8192;
  float* h1     = (float*)alloc(8 * 1024 * 4);
  float* h2     = (float*)alloc(8 * 1024 * 4);
  float* gq     = (float*)alloc(8 * 16 * 64 * 4);
  float* qa_b_pad = (float*)alloc(128 * 4);

  float* out0 = (float*)d_out;                    // [M][D] final output / attn_out
  float* attn = (float*)d_out + (size_t)M * D;    // [B*H][N] attention maps

  const dim3 tb(32, 8);
  // weight transposes -> bf16 [N][K]
  hipLaunchKernelGGL(transpose_bf16_k, dim3(32, 32), tb, 0, stream, wq_w, wqT, D, D);
  hipLaunchKernelGGL(transpose_bf16_k, dim3(32, 32), tb, 0, stream, wk_w, wkT, D, D);
  hipLaunchKernelGGL(transpose_bf16_k, dim3(32, 32), tb, 0, stream, wv_w, wvT, D, D);
  hipLaunchKernelGGL(transpose_bf16_k, dim3(32, 32), tb, 0, stream, out_w, woT, D, D);
  hipLaunchKernelGGL(transpose_bf16_k, dim3(128, 32), tb, 0, stream, mlp_w1, w1T, D, MLPD);
  hipLaunchKernelGGL(transpose_bf16_k, dim3(32, 128), tb, 0, stream, mlp_w2, w2T, MLPD, D);
  hipLaunchKernelGGL(transpose_bf16_k, dim3(1, 32), tb, 0, stream, qa_w, qaT, D, 16);
  hipLaunchKernelGGL(pad_bias_k, dim3(1), dim3(128), 0, stream, qa_b, qa_b_pad);

  // conditioning: zero accs, then K-split skinny GEMMs + epilogues
  hipLaunchKernelGGL(zero_k, dim3(48), dim3(256), 0, stream, (float4*)cacc);
  hipLaunchKernelGGL(skinny_k<1>, dim3(16, 16), dim3(256), 0, stream, z, n1_hw, (const float*)nullptr, accH1, (float*)nullptr);
  hipLaunchKernelGGL(h_epi_k, dim3(32), dim3(256), 0, stream, accH1, n1_hb, h1);
  hipLaunchKernelGGL(skinny_k<2>, dim3(16, 16), dim3(256), 0, stream, h1, n1_gw, n1_bw, accS1, accT1);
  hipLaunchKernelGGL(skinny_k<1>, dim3(16, 16), dim3(256), 0, stream, z, n2_hw, (const float*)nullptr, accH2, (float*)nullptr);
  hipLaunchKernelGGL(h_epi_k, dim3(32), dim3(256), 0, stream, accH2, n2_hb, h2);
  hipLaunchKernelGGL(skinny_k<2>, dim3(16, 16), dim3(256), 0, stream, h2, n2_gw, n2_bw, accS2, accT2);

  // LN1 -> xn (bf16)
  hipLaunchKernelGGL(ln_mod_k, dim3(M / 4), dim3(256), 0, stream, inputs, accS1, accT1, n1_gb, n1_bb, xn);

  // Q, K, V
  hipLaunchKernelGGL(gemm_bf16<0>, dim3(8, 64), dim3(256), 0, stream, xn, wqT, wq_b, (const float*)nullptr, (void*)Qb, M, D, D);
  hipLaunchKernelGGL(gemm_bf16<0>, dim3(8, 64), dim3(256), 0, stream, xn, wkT, wk_b, (const float*)nullptr, (void*)Kb, M, D, D);
  hipLaunchKernelGGL(gemm_bf16<0>, dim3(8, 64), dim3(256), 0, stream, xn, wvT, wv_b, (const float*)nullptr, (void*)Vb, M, D, D);

  // logits = Q @ qa_w + qa_b (padded to N=128)
  hipLaunchKernelGGL(gemm_bf16<3>, dim3(1, 64), dim3(256), 0, stream, Qb, qaT, qa_b_pad, (const float*)nullptr, (void*)logits, M, 128, D);

  // softmax -> attn maps (written straight into d_out region 1)
  hipLaunchKernelGGL(softmax_k, dim3(128), dim3(256), 0, stream, logits, attn);

  // global_q
  hipLaunchKernelGGL(global_q_k, dim3(128), dim3(256), 0, stream, attn, Qb, gq);

  // r = gq * K * V (in-place over K buffer)
  hipLaunchKernelGGL(r_k, dim3(M * D / 8 / 256), dim3(256), 0, stream, Kb, Vb, gq, Kb);

  // attn_out = inputs + r @ out_w + out_b  -> d_out region 0 (f32)
  hipLaunchKernelGGL(gemm_bf16<2>, dim3(8, 64), dim3(256), 0, stream, Kb, woT, out_b, inputs, (void*)out0, M, D, D);

  // LN2 -> xn (bf16)
  hipLaunchKernelGGL(ln_mod_k, dim3(M / 4), dim3(256), 0, stream, out0, accS2, accT2, n2_gb, n2_bb, xn);

  // MLP1 + exact gelu -> hbuf (bf16)
  hipLaunchKernelGGL(gemm_bf16<1>, dim3(32, 64), dim3(256), 0, stream, xn, w1T, mlp_b1, (const float*)nullptr, (void*)hbuf, M, MLPD, D);

  // MLP2 + attn_out residual -> final output (f32, in-place RMW on d_out)
  hipLaunchKernelGGL(gemm_bf16<2>, dim3(8, 64), dim3(256), 0, stream, hbuf, w2T, mlp_b2, out0, (void*)out0, M, D, MLPD);
}